// Round 4
// baseline (50.783 us; speedup 1.0000x reference)
//
#include <hip/hip_runtime.h>
#include <hip/hip_bf16.h>

// out[i] = exp(-0.5 * 0.54 * |x[i] - mu|^2), x: [N,2] f32, mu: [2] f32, out: [N] f32
// Memory-bound elementwise. Exact-fit flat grid, 8 points per thread:
// 4x float4 non-temporal loads (64 B) + 2x float4 non-temporal stores (32 B).
// Non-temporal: zero-reuse stream, don't pollute L2/LLC.
// NOTE: __builtin_nontemporal_* needs a native clang vector type, not
// HIP_vector_type<float,4> — use ext_vector_type(4).

typedef float v4f __attribute__((ext_vector_type(4)));

__global__ __launch_bounds__(256) void MyGaussianPDF_75479755260306_kernel(
    const v4f* __restrict__ x4,   // [N/2] v4f = 2 points each
    const float* __restrict__ mu, // [2]
    v4f* __restrict__ out4)       // [N/4]
{
    const float m0 = mu[0];
    const float m1 = mu[1];
    // exp(-0.27 * s) == exp2(-0.27 * log2(e) * s)
    const float k = -0.5f * 0.54f * 1.44269504088896340736f;

    // 8 points per thread = 2 consecutive out-float4 tiles.
    const long long t = (long long)blockIdx.x * blockDim.x + threadIdx.x;

    v4f a0 = __builtin_nontemporal_load(&x4[4 * t + 0]);   // points 0,1
    v4f a1 = __builtin_nontemporal_load(&x4[4 * t + 1]);   // points 2,3
    v4f a2 = __builtin_nontemporal_load(&x4[4 * t + 2]);   // points 4,5
    v4f a3 = __builtin_nontemporal_load(&x4[4 * t + 3]);   // points 6,7

    v4f r0, r1;
    {
        float dx0 = a0.x - m0, dy0 = a0.y - m1;
        float dx1 = a0.z - m0, dy1 = a0.w - m1;
        float dx2 = a1.x - m0, dy2 = a1.y - m1;
        float dx3 = a1.z - m0, dy3 = a1.w - m1;
        r0.x = exp2f(k * (dx0 * dx0 + dy0 * dy0));
        r0.y = exp2f(k * (dx1 * dx1 + dy1 * dy1));
        r0.z = exp2f(k * (dx2 * dx2 + dy2 * dy2));
        r0.w = exp2f(k * (dx3 * dx3 + dy3 * dy3));
    }
    {
        float dx0 = a2.x - m0, dy0 = a2.y - m1;
        float dx1 = a2.z - m0, dy1 = a2.w - m1;
        float dx2 = a3.x - m0, dy2 = a3.y - m1;
        float dx3 = a3.z - m0, dy3 = a3.w - m1;
        r1.x = exp2f(k * (dx0 * dx0 + dy0 * dy0));
        r1.y = exp2f(k * (dx1 * dx1 + dy1 * dy1));
        r1.z = exp2f(k * (dx2 * dx2 + dy2 * dy2));
        r1.w = exp2f(k * (dx3 * dx3 + dy3 * dy3));
    }

    __builtin_nontemporal_store(r0, &out4[2 * t + 0]);
    __builtin_nontemporal_store(r1, &out4[2 * t + 1]);
}

extern "C" void kernel_launch(void* const* d_in, const int* in_sizes, int n_in,
                              void* d_out, int out_size, void* d_ws, size_t ws_size,
                              hipStream_t stream) {
    const float* x  = (const float*)d_in[0];   // [N,2]
    const float* mu = (const float*)d_in[1];   // [2]
    float* out = (float*)d_out;                // [N]

    const int N = out_size;          // 16777216 = 2^24
    const int block = 256;
    const int pts_per_thread = 8;
    const int grid = N / (block * pts_per_thread);   // 8192 blocks, exact fit

    MyGaussianPDF_75479755260306_kernel<<<grid, block, 0, stream>>>(
        (const v4f*)x, mu, (v4f*)out);
}

// Round 5
// 33.757 us; speedup vs baseline: 1.5043x; 1.5043x over previous
//
#include <hip/hip_runtime.h>
#include <hip/hip_bf16.h>

// out[i] = exp(-0.5 * 0.54 * |x[i] - mu|^2), x: [N,2] f32, mu: [2] f32, out: [N] f32
// Memory-bound elementwise. Exact-fit flat grid, 8 points per thread:
// 4x float4 loads (64 B) + 2x float4 stores (32 B), no grid-stride loop.
//
// R4 post-mortem note: do NOT use __builtin_nontemporal_* here — the 192 MiB
// working set fits the 256 MiB Infinity Cache, and LLC residency across timed
// replays is worth ~1.5x (NT version measured 50.8 us vs 33.8 us cached).

__global__ __launch_bounds__(256) void MyGaussianPDF_75479755260306_kernel(
    const float4* __restrict__ x4,   // [N/2] float4 = 2 points each
    const float* __restrict__ mu,    // [2]
    float4* __restrict__ out4)       // [N/4]
{
    const float m0 = mu[0];
    const float m1 = mu[1];
    // exp(-0.27 * s) == exp2(-0.27 * log2(e) * s)
    const float k = -0.5f * 0.54f * 1.44269504088896340736f;

    // 8 points per thread = 2 consecutive out-float4 tiles.
    const long long t = (long long)blockIdx.x * blockDim.x + threadIdx.x;

    float4 a0 = x4[4 * t + 0];   // points 0,1
    float4 a1 = x4[4 * t + 1];   // points 2,3
    float4 a2 = x4[4 * t + 2];   // points 4,5
    float4 a3 = x4[4 * t + 3];   // points 6,7

    float4 r0, r1;
    {
        float dx0 = a0.x - m0, dy0 = a0.y - m1;
        float dx1 = a0.z - m0, dy1 = a0.w - m1;
        float dx2 = a1.x - m0, dy2 = a1.y - m1;
        float dx3 = a1.z - m0, dy3 = a1.w - m1;
        r0.x = exp2f(k * (dx0 * dx0 + dy0 * dy0));
        r0.y = exp2f(k * (dx1 * dx1 + dy1 * dy1));
        r0.z = exp2f(k * (dx2 * dx2 + dy2 * dy2));
        r0.w = exp2f(k * (dx3 * dx3 + dy3 * dy3));
    }
    {
        float dx0 = a2.x - m0, dy0 = a2.y - m1;
        float dx1 = a2.z - m0, dy1 = a2.w - m1;
        float dx2 = a3.x - m0, dy2 = a3.y - m1;
        float dx3 = a3.z - m0, dy3 = a3.w - m1;
        r1.x = exp2f(k * (dx0 * dx0 + dy0 * dy0));
        r1.y = exp2f(k * (dx1 * dx1 + dy1 * dy1));
        r1.z = exp2f(k * (dx2 * dx2 + dy2 * dy2));
        r1.w = exp2f(k * (dx3 * dx3 + dy3 * dy3));
    }

    out4[2 * t + 0] = r0;
    out4[2 * t + 1] = r1;
}

extern "C" void kernel_launch(void* const* d_in, const int* in_sizes, int n_in,
                              void* d_out, int out_size, void* d_ws, size_t ws_size,
                              hipStream_t stream) {
    const float* x  = (const float*)d_in[0];   // [N,2]
    const float* mu = (const float*)d_in[1];   // [2]
    float* out = (float*)d_out;                // [N]

    const int N = out_size;          // 16777216 = 2^24
    const int block = 256;
    const int pts_per_thread = 8;
    const int grid = N / (block * pts_per_thread);   // 8192 blocks, exact fit

    MyGaussianPDF_75479755260306_kernel<<<grid, block, 0, stream>>>(
        (const float4*)x, mu, (float4*)out);
}